// Round 9
// baseline (487.051 us; speedup 1.0000x reference)
//
#include <hip/hip_runtime.h>

// MoE fused kernel, MI355X gfx950 — Round 12: N=64 wave tile + expert-split
// wave halves + per-wave phase stagger + setprio.
// Shapes: B=65536, D=512, C=101, E=8, H=256.
// out[b,c] = sum_{e,h} g[b,e]*relu(x@W1+b1)[b,e,h]*W2[e,h,c] + sum_e g[b,e]*b2[e,c]
// g = softmax(x@Wg+bg), gate logits folded into layer1 GEMM as cols 2048..2055.
//
// R11 post-mortem: explicit reg-dbuf folded away by compiler (VGPR stayed 88),
// +4% only. Serial model confirmed: per block L1-MFMA 40K + L1-LDS 32K +
// L1-L2 37K + hA 12K + L2-phase 31K ~= 152K cyc = 63us x4 blocks/CU = 253
// (meas 246-257). Pipes serialize because all waves run identical
// load->wait->MFMA cadence from common barrier starts (convoy); R7's 4
// waves/SIMD proved phase-locked TLP hides nothing. R12, on the R8 skeleton
// (ct-owned acc2[4]=16 persistent regs, 2 barriers/it):
//  (1) N=64/wave, experts SPLIT across wave halves (w<4: e=2it, w>=4: e=2it+1)
//      acc1[4][4] transient -> per-expert LDS A-reads 512->256KB (L1-LDS
//      16K cyc), W1-L2 unchanged (b still wave-exclusive), MFMA unchanged.
//  (2) phase stagger: K-loops are order-independent -> kf=(i+2w)&15. SIMD
//      mates (w,w+4) run 8 steps anti-phased + different operand streams ->
//      one wave's LDS/L2 burst overlaps the other's MFMA phase.
//  (3) s_setprio(1) around MFMA clusters (T5) — stagger creates the role
//      diversity it needs; null in lockstep so worst-case free.
// Tripwire: WRITE_SIZE>100MB = acc1[4][4] spill -> back to [4][2]+stagger.
// Null branch: dur~240 MfmaUtil~30 -> R13 = 2-phase staged-W1 counted-vmcnt.
//
// MFMA layouts (m89/m120-verified):
//   A: A[m][k], m=lane&15, k=(lane>>4)*8+j (j=0..7)
//   B: B[k][n], n=lane&15, k=(lane>>4)*8+j
//   C/D: col=lane&15, row=(lane>>4)*4+reg

typedef __attribute__((ext_vector_type(8))) short short8x;
typedef __attribute__((ext_vector_type(4))) float float4x;

#define C_DIM 101

__device__ __forceinline__ unsigned short f2bf(float f) {
  unsigned int u = __builtin_bit_cast(unsigned int, f);
  u += 0x7fffu + ((u >> 16) & 1u);     // round-to-nearest-even
  return (unsigned short)(u >> 16);
}

// ---- merged weight conversion (one launch)
// W1 (+Wg) -> bf16 B-frags: frag = ntile*16+kf ; elem = frag*512 + lane*8 + j
// W2       -> bf16 B-frags: frag = ntile*64+kf ; ntile 0..7, kf 0..63 (K=2048)
__global__ void conv_weights(const float* __restrict__ W1, const float* __restrict__ Wg,
                             const float* __restrict__ W2,
                             unsigned short* __restrict__ W1bf,
                             unsigned short* __restrict__ W2bf) {
  if (blockIdx.x < 516) {
    int s = blockIdx.x * blockDim.x + threadIdx.x;   // slot = frag*64 + lane
    int l = s & 63;
    int frag = s >> 6;
    int kf = frag & 15;
    int ntile = frag >> 4;
    int n = (ntile << 4) | (l & 15);
    int k = (kf << 5) | ((l >> 4) << 3);
    short8x v;
#pragma unroll
    for (int j = 0; j < 8; ++j) {
      int kk = k + j;
      float f;
      if (n < 2048)      f = W1[((size_t)(n >> 8) * 512 + kk) * 256 + (n & 255)];
      else if (n < 2056) f = Wg[(size_t)kk * 8 + (n - 2048)];
      else               f = 0.f;
      v[j] = (short)f2bf(f);
    }
    *(short8x*)(W1bf + (size_t)s * 8) = v;
  } else {
    int s = (blockIdx.x - 516) * blockDim.x + threadIdx.x;
    int l = s & 63;
    int frag = s >> 6;
    int kf = frag & 63;
    int ntile = frag >> 6;
    int c = (ntile << 4) | (l & 15);
    int k = (kf << 5) | ((l >> 4) << 3);
    short8x v;
#pragma unroll
    for (int j = 0; j < 8; ++j) {
      int kk = k + j;                       // e = kk>>8, h = kk&255
      float f = (c < C_DIM) ? W2[((size_t)(kk >> 8) * 256 + (kk & 255)) * C_DIM + c] : 0.f;
      v[j] = (short)f2bf(f);
    }
    *(short8x*)(W2bf + (size_t)s * 8) = v;
  }
}

// ---- fused main kernel: 64 rows/block, 512 threads (8 waves), 1 block/CU
__global__ __launch_bounds__(512, 2) void moe_main(
    const float* __restrict__ x, const float* __restrict__ b1,
    const float* __restrict__ b2, const float* __restrict__ bg,
    const unsigned short* __restrict__ W1bf, const unsigned short* __restrict__ W2bf,
    float* __restrict__ out) {
  __shared__ unsigned short xA[64 * 512];   // 64 KB: x A-frags [mt*16+kf][lane*8+j]
  __shared__ unsigned short hA[64 * 512];   // 64 KB: 2 experts x 32 h' A-frags
  __shared__ float gt[8 * 64];              //  2 KB: gates^T [e][row]
  float* graw = (float*)hA;                 // raw gate logits [64][8]; pre-loop only

  const int tid = threadIdx.x;
  const int w = tid >> 6;     // wave 0..7
  const int l = tid & 63;     // lane
  const int quad = l >> 4;
  const int p = l & 15;
  const int r0 = blockIdx.x * 64;
  const int eo = w >> 2;      // which expert of the pair this wave works
  const int wq = w & 3;       // col quarter (64 cols) within the expert
  const int st = w * 2;       // per-wave K-loop phase stagger (SIMD-mates 8 apart)

  // ---- stage x -> bf16 A-frag LDS (coalesced float4 x2 reads, b128 LDS writes)
#pragma unroll
  for (int it = 0; it < 8; ++it) {
    int g = tid + it * 512;            // m = g>>6 (0..63), k0 = (g&63)*8
    int m = g >> 6;
    int k0 = (g & 63) << 3;
    const float* src = x + (size_t)(r0 + m) * 512 + k0;
    float4 f0 = *(const float4*)src;
    float4 f1 = *(const float4*)(src + 4);
    short8x v;
    v[0] = (short)f2bf(f0.x); v[1] = (short)f2bf(f0.y);
    v[2] = (short)f2bf(f0.z); v[3] = (short)f2bf(f0.w);
    v[4] = (short)f2bf(f1.x); v[5] = (short)f2bf(f1.y);
    v[6] = (short)f2bf(f1.z); v[7] = (short)f2bf(f1.w);
    int mt = m >> 4;
    int kfrag = k0 >> 5;
    int lane = (((k0 >> 3) & 3) << 4) | (m & 15);
    *(short8x*)&xA[(size_t)(((mt << 4) | kfrag) * 64 + lane) * 8] = v;
  }
  __syncthreads();

  // ---- gate logits: waves 0..3 each do one 16-row tile x 16 gate cols (ntile 128)
  if (w < 4) {
    float4x acc = {0.f, 0.f, 0.f, 0.f};
#pragma unroll 2
    for (int kf = 0; kf < 16; ++kf) {
      short8x a = *(const short8x*)&xA[(size_t)((w * 16 + kf) * 64 + l) * 8];
      short8x b = *(const short8x*)(W1bf + ((size_t)(128 * 16 + kf) * 512 + l * 8));
      acc = __builtin_amdgcn_mfma_f32_16x16x32_bf16(a, b, acc, 0, 0, 0);
    }
    if (p < 8) {
      float bgv = bg[p];
#pragma unroll
      for (int r = 0; r < 4; ++r)
        graw[(w * 16 + quad * 4 + r) * 8 + p] = acc[r] + bgv;
    }
  }
  __syncthreads();
  // softmax over E=8 per row, fp32; write transposed gt[e][row]
  if (tid < 64) {
    float v[8], mx = -1e30f;
#pragma unroll
    for (int e = 0; e < 8; ++e) { v[e] = graw[tid * 8 + e]; mx = fmaxf(mx, v[e]); }
    float s = 0.f;
#pragma unroll
    for (int e = 0; e < 8; ++e) { v[e] = expf(v[e] - mx); s += v[e]; }
    float inv = 1.f / s;
#pragma unroll
    for (int e = 0; e < 8; ++e) gt[e * 64 + tid] = v[e] * inv;
  }
  __syncthreads();   // graw (hA alias) reads done before first hA write

  // ---- main loop: 4 iterations, 2 experts each (CONCURRENT via wave halves)
  float4x zero = {0.f, 0.f, 0.f, 0.f};
  float4x acc2[4];                       // [mt]; wave w owns output col-tile ct=w (w<7)
  acc2[0] = zero; acc2[1] = zero; acc2[2] = zero; acc2[3] = zero;

  for (int it = 0; it < 4; ++it) {
    const int e = it * 2 + eo;
    // layer1: wave (eo,wq) = ALL 64 rows x h-cols [e*256 + wq*64, +64)
    float4x acc1[4][4];                  // [mt][nc] transient
#pragma unroll
    for (int mt = 0; mt < 4; ++mt)
#pragma unroll
      for (int nc = 0; nc < 4; ++nc) acc1[mt][nc] = zero;

    const unsigned short* __restrict__ bp =
        W1bf + ((size_t)(e * 16 + wq * 4) * 16) * 512 + (size_t)l * 8;
    // b-frag (nc,kf) at bp + (nc*16 + kf)*512 shorts
#pragma unroll
    for (int i = 0; i < 16; ++i) {
      const int kf = (i + st) & 15;      // staggered, order-independent sum
      short8x b0 = *(const short8x*)(bp + (0 * 16 + kf) * 512);
      short8x b1f = *(const short8x*)(bp + (1 * 16 + kf) * 512);
      short8x b2f = *(const short8x*)(bp + (2 * 16 + kf) * 512);
      short8x b3f = *(const short8x*)(bp + (3 * 16 + kf) * 512);
      short8x a0 = *(const short8x*)&xA[(size_t)((0 * 16 + kf) * 64 + l) * 8];
      short8x a1 = *(const short8x*)&xA[(size_t)((1 * 16 + kf) * 64 + l) * 8];
      short8x a2 = *(const short8x*)&xA[(size_t)((2 * 16 + kf) * 64 + l) * 8];
      short8x a3 = *(const short8x*)&xA[(size_t)((3 * 16 + kf) * 64 + l) * 8];
      __builtin_amdgcn_s_setprio(1);
      acc1[0][0] = __builtin_amdgcn_mfma_f32_16x16x32_bf16(a0, b0, acc1[0][0], 0, 0, 0);
      acc1[1][0] = __builtin_amdgcn_mfma_f32_16x16x32_bf16(a1, b0, acc1[1][0], 0, 0, 0);
      acc1[2][0] = __builtin_amdgcn_mfma_f32_16x16x32_bf16(a2, b0, acc1[2][0], 0, 0, 0);
      acc1[3][0] = __builtin_amdgcn_mfma_f32_16x16x32_bf16(a3, b0, acc1[3][0], 0, 0, 0);
      acc1[0][1] = __builtin_amdgcn_mfma_f32_16x16x32_bf16(a0, b1f, acc1[0][1], 0, 0, 0);
      acc1[1][1] = __builtin_amdgcn_mfma_f32_16x16x32_bf16(a1, b1f, acc1[1][1], 0, 0, 0);
      acc1[2][1] = __builtin_amdgcn_mfma_f32_16x16x32_bf16(a2, b1f, acc1[2][1], 0, 0, 0);
      acc1[3][1] = __builtin_amdgcn_mfma_f32_16x16x32_bf16(a3, b1f, acc1[3][1], 0, 0, 0);
      acc1[0][2] = __builtin_amdgcn_mfma_f32_16x16x32_bf16(a0, b2f, acc1[0][2], 0, 0, 0);
      acc1[1][2] = __builtin_amdgcn_mfma_f32_16x16x32_bf16(a1, b2f, acc1[1][2], 0, 0, 0);
      acc1[2][2] = __builtin_amdgcn_mfma_f32_16x16x32_bf16(a2, b2f, acc1[2][2], 0, 0, 0);
      acc1[3][2] = __builtin_amdgcn_mfma_f32_16x16x32_bf16(a3, b2f, acc1[3][2], 0, 0, 0);
      acc1[0][3] = __builtin_amdgcn_mfma_f32_16x16x32_bf16(a0, b3f, acc1[0][3], 0, 0, 0);
      acc1[1][3] = __builtin_amdgcn_mfma_f32_16x16x32_bf16(a1, b3f, acc1[1][3], 0, 0, 0);
      acc1[2][3] = __builtin_amdgcn_mfma_f32_16x16x32_bf16(a2, b3f, acc1[2][3], 0, 0, 0);
      acc1[3][3] = __builtin_amdgcn_mfma_f32_16x16x32_bf16(a3, b3f, acc1[3][3], 0, 0, 0);
      __builtin_amdgcn_s_setprio(0);
    }

    __syncthreads();                     // BAR1: prev it's layer2 hA reads done

    // epilogue: +b1, relu, *gate(e), bf16 -> hA (C->A transpose)
    // frag = eo*32 + kf2*4 + mt, kf2 = cw>>5 in {wq*2, wq*2+1}
    float4x gv0 = *(const float4x*)&gt[e * 64 + 0  + quad * 4];
    float4x gv1 = *(const float4x*)&gt[e * 64 + 16 + quad * 4];
    float4x gv2 = *(const float4x*)&gt[e * 64 + 32 + quad * 4];
    float4x gv3 = *(const float4x*)&gt[e * 64 + 48 + quad * 4];
#pragma unroll
    for (int nc = 0; nc < 4; ++nc) {
      int cw = wq * 64 + nc * 16 + p;    // h-col within expert tile (0..255)
      float b1v = b1[e * 256 + cw];
      int kf2 = cw >> 5;
      int koff = cw & 31;
      int jj = koff & 7;
      int ldbase = (koff >> 3) << 4;
#pragma unroll
      for (int mt = 0; mt < 4; ++mt) {
        float4x gv = (mt == 0) ? gv0 : (mt == 1) ? gv1 : (mt == 2) ? gv2 : gv3;
#pragma unroll
        for (int r = 0; r < 4; ++r) {
          float hv = fmaxf(acc1[mt][nc][r] + b1v, 0.f) * gv[r];
          hA[(size_t)((eo * 32 + kf2 * 4 + mt) * 512) + (ldbase + quad * 4 + r) * 8 + jj] =
              f2bf(hv);
        }
      }
    }
    __syncthreads();                     // BAR2: both experts' h' published

    // layer2: wave w (<7) accumulates ct=w over both experts' K=512.
    // 16 flat steps s = eo*8+kf2, staggered start; a-frag = hA[s*4+mt]
    if (w < 7) {
      const unsigned short* __restrict__ bp2 =
          W2bf + ((size_t)(w * 64 + it * 16)) * 512 + (size_t)l * 8;
#pragma unroll
      for (int i = 0; i < 16; ++i) {
        const int s = (i + st) & 15;
        short8x b = *(const short8x*)(bp2 + (size_t)s * 512);
        short8x a0 = *(const short8x*)&hA[(size_t)((s * 4 + 0) * 64 + l) * 8];
        short8x a1 = *(const short8x*)&hA[(size_t)((s * 4 + 1) * 64 + l) * 8];
        short8x a2 = *(const short8x*)&hA[(size_t)((s * 4 + 2) * 64 + l) * 8];
        short8x a3 = *(const short8x*)&hA[(size_t)((s * 4 + 3) * 64 + l) * 8];
        __builtin_amdgcn_s_setprio(1);
        acc2[0] = __builtin_amdgcn_mfma_f32_16x16x32_bf16(a0, b, acc2[0], 0, 0, 0);
        acc2[1] = __builtin_amdgcn_mfma_f32_16x16x32_bf16(a1, b, acc2[1], 0, 0, 0);
        acc2[2] = __builtin_amdgcn_mfma_f32_16x16x32_bf16(a2, b, acc2[2], 0, 0, 0);
        acc2[3] = __builtin_amdgcn_mfma_f32_16x16x32_bf16(a3, b, acc2[3], 0, 0, 0);
        __builtin_amdgcn_s_setprio(0);
      }
    }
  }

  // ---- epilogue: + gate-weighted b2, store. No cross-wave reduction.
  if (w < 7) {
    int c = w * 16 + p;
    if (c < C_DIM) {
#pragma unroll
      for (int mt = 0; mt < 4; ++mt) {
#pragma unroll
        for (int r = 0; r < 4; ++r) {
          int row = mt * 16 + quad * 4 + r;
          float bias = 0.f;
#pragma unroll
          for (int e = 0; e < 8; ++e) bias += gt[e * 64 + row] * b2[e * C_DIM + c];
          out[(size_t)(r0 + row) * C_DIM + c] = acc2[mt][r] + bias;
        }
      }
    }
  }
}

extern "C" void kernel_launch(void* const* d_in, const int* in_sizes, int n_in,
                              void* d_out, int out_size, void* d_ws, size_t ws_size,
                              hipStream_t stream) {
  const float* x  = (const float*)d_in[0];
  const float* W1 = (const float*)d_in[1];
  const float* b1 = (const float*)d_in[2];
  const float* W2 = (const float*)d_in[3];
  const float* b2 = (const float*)d_in[4];
  const float* Wg = (const float*)d_in[5];
  const float* bg = (const float*)d_in[6];
  float* out = (float*)d_out;

  unsigned short* W1bf = (unsigned short*)d_ws;
  unsigned short* W2bf = (unsigned short*)((char*)d_ws + (size_t)129 * 16 * 512 * 2);

  conv_weights<<<644, 256, 0, stream>>>(W1, Wg, W2, W1bf, W2bf);  // 516 + 128 blocks
  moe_main<<<1024, 512, 0, stream>>>(x, b1, b2, bg, W1bf, W2bf, out);
}

// Round 10
// 377.266 us; speedup vs baseline: 1.2910x; 1.2910x over previous
//
#include <hip/hip_runtime.h>

// MoE fused kernel, MI355X gfx950 — Round 13: R11 + bulk K-half W1 register
// staging (T14 issue-early/consume-late).
// Shapes: B=65536, D=512, C=101, E=8, H=256.
// out[b,c] = sum_{e,h} g[b,e]*relu(x@W1+b1)[b,e,h]*W2[e,h,c] + sum_e g[b,e]*b2[e,c]
// g = softmax(x@Wg+bg), gate logits folded into layer1 GEMM as cols 2048..2055.
//
// R12 post-mortem: stagger+expert-split spilled (WRITE 235MB, FETCH +48MB,
// 349us) — 4th confirmation that >~48 accumulator regs beyond operands spills.
// Best proven: R8/R11 = 246us, serial model ~152K cyc/block (L2-B 37K +
// LDS-A 49K + MFMA 40K + misc). R13 changes ONLY layer1 b-sourcing on the
// R11 source: bfA[2][8]/bfB[2][8] (128 VGPR) hold the wave's W1 slice one
// K-HALF ahead. Per expert: {issue 16 loads K-half B -> compute K-half A
// (8kf x 4a x 8mfma, LDS pattern IDENTICAL to R8: a read once/kf, both nc
// together) -> issue next expert's K-half A -> compute K-half B}. Bulk
// 64-reg live ranges with uses after a full half-phase force s_waitcnt
// AFTER ~800cy of MFMA+LDS (compiler can't re-sink like R11's per-kf regs).
// Staging BW/half 128KB/CU ~2285cy ~= covered by half compute ~4K cy.
// Regs: 128 buf + 32 acc1 + 16 acc2 + ~50 misc ~= 225 < 256 cap.
// Mechanism check: VGPR_Count must rise to 170-220 (88 = loads sunk = null).
// Tripwire: WRITE_SIZE > 100MB = spill -> revert to R11, structure ceiling.
//
// MFMA layouts (m89/m120-verified):
//   A: A[m][k], m=lane&15, k=(lane>>4)*8+j (j=0..7)
//   B: B[k][n], n=lane&15, k=(lane>>4)*8+j
//   C/D: col=lane&15, row=(lane>>4)*4+reg

typedef __attribute__((ext_vector_type(8))) short short8x;
typedef __attribute__((ext_vector_type(4))) float float4x;

#define C_DIM 101

__device__ __forceinline__ unsigned short f2bf(float f) {
  unsigned int u = __builtin_bit_cast(unsigned int, f);
  u += 0x7fffu + ((u >> 16) & 1u);     // round-to-nearest-even
  return (unsigned short)(u >> 16);
}

// ---- merged weight conversion (one launch)
// W1 (+Wg) -> bf16 B-frags: frag = ntile*16+kf ; elem = frag*512 + lane*8 + j
// W2       -> bf16 B-frags: frag = ntile*64+kf ; ntile 0..7, kf 0..63 (K=2048)
__global__ void conv_weights(const float* __restrict__ W1, const float* __restrict__ Wg,
                             const float* __restrict__ W2,
                             unsigned short* __restrict__ W1bf,
                             unsigned short* __restrict__ W2bf) {
  if (blockIdx.x < 516) {
    int s = blockIdx.x * blockDim.x + threadIdx.x;   // slot = frag*64 + lane
    int l = s & 63;
    int frag = s >> 6;
    int kf = frag & 15;
    int ntile = frag >> 4;
    int n = (ntile << 4) | (l & 15);
    int k = (kf << 5) | ((l >> 4) << 3);
    short8x v;
#pragma unroll
    for (int j = 0; j < 8; ++j) {
      int kk = k + j;
      float f;
      if (n < 2048)      f = W1[((size_t)(n >> 8) * 512 + kk) * 256 + (n & 255)];
      else if (n < 2056) f = Wg[(size_t)kk * 8 + (n - 2048)];
      else               f = 0.f;
      v[j] = (short)f2bf(f);
    }
    *(short8x*)(W1bf + (size_t)s * 8) = v;
  } else {
    int s = (blockIdx.x - 516) * blockDim.x + threadIdx.x;
    int l = s & 63;
    int frag = s >> 6;
    int kf = frag & 63;
    int ntile = frag >> 6;
    int c = (ntile << 4) | (l & 15);
    int k = (kf << 5) | ((l >> 4) << 3);
    short8x v;
#pragma unroll
    for (int j = 0; j < 8; ++j) {
      int kk = k + j;                       // e = kk>>8, h = kk&255
      float f = (c < C_DIM) ? W2[((size_t)(kk >> 8) * 256 + (kk & 255)) * C_DIM + c] : 0.f;
      v[j] = (short)f2bf(f);
    }
    *(short8x*)(W2bf + (size_t)s * 8) = v;
  }
}

// ---- fused main kernel: 64 rows/block, 512 threads (8 waves), 1 block/CU
__global__ __launch_bounds__(512, 2) void moe_main(
    const float* __restrict__ x, const float* __restrict__ b1,
    const float* __restrict__ b2, const float* __restrict__ bg,
    const unsigned short* __restrict__ W1bf, const unsigned short* __restrict__ W2bf,
    float* __restrict__ out) {
  __shared__ unsigned short xA[64 * 512];   // 64 KB: x A-frags [mt*16+kf][lane*8+j]
  __shared__ unsigned short hA[64 * 512];   // 64 KB: 2 experts x 32 h' A-frags
  __shared__ float gt[8 * 64];              //  2 KB: gates^T [e][row]
  float* graw = (float*)hA;                 // raw gate logits [64][8]; pre-loop only

  const int tid = threadIdx.x;
  const int w = tid >> 6;     // wave 0..7
  const int l = tid & 63;     // lane
  const int quad = l >> 4;
  const int p = l & 15;
  const int r0 = blockIdx.x * 64;

  // ---- stage x -> bf16 A-frag LDS (coalesced float4 x2 reads, b128 LDS writes)
#pragma unroll
  for (int it = 0; it < 8; ++it) {
    int g = tid + it * 512;            // m = g>>6 (0..63), k0 = (g&63)*8
    int m = g >> 6;
    int k0 = (g & 63) << 3;
    const float* src = x + (size_t)(r0 + m) * 512 + k0;
    float4 f0 = *(const float4*)src;
    float4 f1 = *(const float4*)(src + 4);
    short8x v;
    v[0] = (short)f2bf(f0.x); v[1] = (short)f2bf(f0.y);
    v[2] = (short)f2bf(f0.z); v[3] = (short)f2bf(f0.w);
    v[4] = (short)f2bf(f1.x); v[5] = (short)f2bf(f1.y);
    v[6] = (short)f2bf(f1.z); v[7] = (short)f2bf(f1.w);
    int mt = m >> 4;
    int kfrag = k0 >> 5;
    int lane = (((k0 >> 3) & 3) << 4) | (m & 15);
    *(short8x*)&xA[(size_t)(((mt << 4) | kfrag) * 64 + lane) * 8] = v;
  }
  __syncthreads();

  // ---- gate logits: waves 0..3 each do one 16-row tile x 16 gate cols (ntile 128)
  if (w < 4) {
    float4x acc = {0.f, 0.f, 0.f, 0.f};
#pragma unroll 2
    for (int kf = 0; kf < 16; ++kf) {
      short8x a = *(const short8x*)&xA[(size_t)((w * 16 + kf) * 64 + l) * 8];
      short8x b = *(const short8x*)(W1bf + ((size_t)(128 * 16 + kf) * 512 + l * 8));
      acc = __builtin_amdgcn_mfma_f32_16x16x32_bf16(a, b, acc, 0, 0, 0);
    }
    if (p < 8) {
      float bgv = bg[p];
#pragma unroll
      for (int r = 0; r < 4; ++r)
        graw[(w * 16 + quad * 4 + r) * 8 + p] = acc[r] + bgv;
    }
  }
  __syncthreads();
  // softmax over E=8 per row, fp32; write transposed gt[e][row]
  if (tid < 64) {
    float v[8], mx = -1e30f;
#pragma unroll
    for (int e = 0; e < 8; ++e) { v[e] = graw[tid * 8 + e]; mx = fmaxf(mx, v[e]); }
    float s = 0.f;
#pragma unroll
    for (int e = 0; e < 8; ++e) { v[e] = expf(v[e] - mx); s += v[e]; }
    float inv = 1.f / s;
#pragma unroll
    for (int e = 0; e < 8; ++e) gt[e * 64 + tid] = v[e] * inv;
  }
  __syncthreads();   // graw (hA alias) reads done before first hA write

  // ---- main loop: 4 iterations, 2 experts each. acc2 = ct-owned full-K sum.
  float4x zero = {0.f, 0.f, 0.f, 0.f};
  float4x acc2[4];                       // [mt]; wave w owns output col-tile ct=w (w<7)
  acc2[0] = zero; acc2[1] = zero; acc2[2] = zero; acc2[3] = zero;

  // bulk W1 register staging: wave's 2 ntiles x 8 kf per K-half (64 VGPR each)
  short8x bfA[2][8], bfB[2][8];
  {
    const unsigned short* __restrict__ bp0 =
        W1bf + ((size_t)(0 * 16 + w * 2) * 16) * 512 + (size_t)l * 8;
#pragma unroll
    for (int nc = 0; nc < 2; ++nc)
#pragma unroll
      for (int kf = 0; kf < 8; ++kf)
        bfA[nc][kf] = *(const short8x*)(bp0 + (nc * 16 + kf) * 512);
  }

  for (int it = 0; it < 4; ++it) {
#pragma unroll
    for (int eo = 0; eo < 2; ++eo) {
      const int e = it * 2 + eo;
      // layer1: wave w covers h-cols [e*256 + w*32, +32), all 64 rows.
      float4x acc1[4][2];                // [mt][nc]
#pragma unroll
      for (int mt = 0; mt < 4; ++mt) { acc1[mt][0] = zero; acc1[mt][1] = zero; }

      const unsigned short* __restrict__ bp =
          W1bf + ((size_t)(e * 16 + w * 2) * 16) * 512 + (size_t)l * 8;
      // ISSUE: K-half B (kf 8..15) of THIS expert -> bfB (consumed after half-A)
#pragma unroll
      for (int nc = 0; nc < 2; ++nc)
#pragma unroll
        for (int kf = 0; kf < 8; ++kf)
          bfB[nc][kf] = *(const short8x*)(bp + (nc * 16 + 8 + kf) * 512);

      // COMPUTE: K-half A (kf 0..7) from bfA — a-frags once per kf, both nc
#pragma unroll
      for (int kf = 0; kf < 8; ++kf) {
        short8x a0 = *(const short8x*)&xA[(size_t)((0 * 16 + kf) * 64 + l) * 8];
        short8x a1 = *(const short8x*)&xA[(size_t)((1 * 16 + kf) * 64 + l) * 8];
        short8x a2 = *(const short8x*)&xA[(size_t)((2 * 16 + kf) * 64 + l) * 8];
        short8x a3 = *(const short8x*)&xA[(size_t)((3 * 16 + kf) * 64 + l) * 8];
        acc1[0][0] = __builtin_amdgcn_mfma_f32_16x16x32_bf16(a0, bfA[0][kf], acc1[0][0], 0, 0, 0);
        acc1[1][0] = __builtin_amdgcn_mfma_f32_16x16x32_bf16(a1, bfA[0][kf], acc1[1][0], 0, 0, 0);
        acc1[2][0] = __builtin_amdgcn_mfma_f32_16x16x32_bf16(a2, bfA[0][kf], acc1[2][0], 0, 0, 0);
        acc1[3][0] = __builtin_amdgcn_mfma_f32_16x16x32_bf16(a3, bfA[0][kf], acc1[3][0], 0, 0, 0);
        acc1[0][1] = __builtin_amdgcn_mfma_f32_16x16x32_bf16(a0, bfA[1][kf], acc1[0][1], 0, 0, 0);
        acc1[1][1] = __builtin_amdgcn_mfma_f32_16x16x32_bf16(a1, bfA[1][kf], acc1[1][1], 0, 0, 0);
        acc1[2][1] = __builtin_amdgcn_mfma_f32_16x16x32_bf16(a2, bfA[1][kf], acc1[2][1], 0, 0, 0);
        acc1[3][1] = __builtin_amdgcn_mfma_f32_16x16x32_bf16(a3, bfA[1][kf], acc1[3][1], 0, 0, 0);
      }

      // ISSUE: next expert's K-half A -> bfA (consumed after half-B + epilogue)
      if (e < 7) {
        const unsigned short* __restrict__ bpn =
            W1bf + ((size_t)((e + 1) * 16 + w * 2) * 16) * 512 + (size_t)l * 8;
#pragma unroll
        for (int nc = 0; nc < 2; ++nc)
#pragma unroll
          for (int kf = 0; kf < 8; ++kf)
            bfA[nc][kf] = *(const short8x*)(bpn + (nc * 16 + kf) * 512);
      }

      // COMPUTE: K-half B (kf 8..15) from bfB
#pragma unroll
      for (int kf = 0; kf < 8; ++kf) {
        short8x a0 = *(const short8x*)&xA[(size_t)((0 * 16 + 8 + kf) * 64 + l) * 8];
        short8x a1 = *(const short8x*)&xA[(size_t)((1 * 16 + 8 + kf) * 64 + l) * 8];
        short8x a2 = *(const short8x*)&xA[(size_t)((2 * 16 + 8 + kf) * 64 + l) * 8];
        short8x a3 = *(const short8x*)&xA[(size_t)((3 * 16 + 8 + kf) * 64 + l) * 8];
        acc1[0][0] = __builtin_amdgcn_mfma_f32_16x16x32_bf16(a0, bfB[0][kf], acc1[0][0], 0, 0, 0);
        acc1[1][0] = __builtin_amdgcn_mfma_f32_16x16x32_bf16(a1, bfB[0][kf], acc1[1][0], 0, 0, 0);
        acc1[2][0] = __builtin_amdgcn_mfma_f32_16x16x32_bf16(a2, bfB[0][kf], acc1[2][0], 0, 0, 0);
        acc1[3][0] = __builtin_amdgcn_mfma_f32_16x16x32_bf16(a3, bfB[0][kf], acc1[3][0], 0, 0, 0);
        acc1[0][1] = __builtin_amdgcn_mfma_f32_16x16x32_bf16(a0, bfB[1][kf], acc1[0][1], 0, 0, 0);
        acc1[1][1] = __builtin_amdgcn_mfma_f32_16x16x32_bf16(a1, bfB[1][kf], acc1[1][1], 0, 0, 0);
        acc1[2][1] = __builtin_amdgcn_mfma_f32_16x16x32_bf16(a2, bfB[1][kf], acc1[2][1], 0, 0, 0);
        acc1[3][1] = __builtin_amdgcn_mfma_f32_16x16x32_bf16(a3, bfB[1][kf], acc1[3][1], 0, 0, 0);
      }

      if (eo == 0) __syncthreads();      // BAR1: prev iteration's layer2 hA reads done

      // epilogue: +b1, relu, *gate(e), bf16 -> hA[eo] (C->A transpose)
      // wave w's 32 cols form exactly K-frag kf2=w; frag = eo*32 + w*4 + mt
      float4x gv0 = *(const float4x*)&gt[e * 64 + 0  + quad * 4];
      float4x gv1 = *(const float4x*)&gt[e * 64 + 16 + quad * 4];
      float4x gv2 = *(const float4x*)&gt[e * 64 + 32 + quad * 4];
      float4x gv3 = *(const float4x*)&gt[e * 64 + 48 + quad * 4];
#pragma unroll
      for (int nc = 0; nc < 2; ++nc) {
        int cw = w * 32 + nc * 16 + p;   // col within expert tile (0..255)
        float b1v = b1[e * 256 + cw];
        int jj = p & 7;
        int ldbase = ((nc * 2 + (p >> 3)) << 4);   // (koff>>3)*16, koff = nc*16+p
#pragma unroll
        for (int mt = 0; mt < 4; ++mt) {
          float4x gv = (mt == 0) ? gv0 : (mt == 1) ? gv1 : (mt == 2) ? gv2 : gv3;
#pragma unroll
          for (int r = 0; r < 4; ++r) {
            float hv = fmaxf(acc1[mt][nc][r] + b1v, 0.f) * gv[r];
            hA[(size_t)((eo * 32 + w * 4 + mt) * 512) + (ldbase + quad * 4 + r) * 8 + jj] =
                f2bf(hv);
          }
        }
      }
    }
    __syncthreads();                     // BAR2: both experts' h' published

    // layer2: wave w (<7) accumulates ct=w over both experts' K=512.
    // ONE-STEP PIPELINE over 16 flat steps s = eo*8+kf2: a[4]+b[1] ahead.
    if (w < 7) {
      const unsigned short* __restrict__ bp2 =
          W2bf + ((size_t)(w * 64 + it * 16)) * 512 + (size_t)l * 8;
      // W2 frag offset from bp2 = s*512 ; hA a-frag index = s*4 + mt
      short8x b2C = *(const short8x*)(bp2);
      short8x a2C0 = *(const short8x*)&hA[(size_t)((0 * 4 + 0) * 64 + l) * 8];
      short8x a2C1 = *(const short8x*)&hA[(size_t)((0 * 4 + 1) * 64 + l) * 8];
      short8x a2C2 = *(const short8x*)&hA[(size_t)((0 * 4 + 2) * 64 + l) * 8];
      short8x a2C3 = *(const short8x*)&hA[(size_t)((0 * 4 + 3) * 64 + l) * 8];
#pragma unroll
      for (int s = 0; s < 16; ++s) {
        short8x b2N, a2N0, a2N1, a2N2, a2N3;
        if (s < 15) {
          b2N = *(const short8x*)(bp2 + (size_t)(s + 1) * 512);
          a2N0 = *(const short8x*)&hA[(size_t)(((s + 1) * 4 + 0) * 64 + l) * 8];
          a2N1 = *(const short8x*)&hA[(size_t)(((s + 1) * 4 + 1) * 64 + l) * 8];
          a2N2 = *(const short8x*)&hA[(size_t)(((s + 1) * 4 + 2) * 64 + l) * 8];
          a2N3 = *(const short8x*)&hA[(size_t)(((s + 1) * 4 + 3) * 64 + l) * 8];
        }
        acc2[0] = __builtin_amdgcn_mfma_f32_16x16x32_bf16(a2C0, b2C, acc2[0], 0, 0, 0);
        acc2[1] = __builtin_amdgcn_mfma_f32_16x16x32_bf16(a2C1, b2C, acc2[1], 0, 0, 0);
        acc2[2] = __builtin_amdgcn_mfma_f32_16x16x32_bf16(a2C2, b2C, acc2[2], 0, 0, 0);
        acc2[3] = __builtin_amdgcn_mfma_f32_16x16x32_bf16(a2C3, b2C, acc2[3], 0, 0, 0);
        if (s < 15) {
          a2C0 = a2N0; a2C1 = a2N1; a2C2 = a2N2; a2C3 = a2N3;
          b2C = b2N;
        }
      }
    }
  }

  // ---- epilogue: + gate-weighted b2, store. No cross-wave reduction.
  if (w < 7) {
    int c = w * 16 + p;
    if (c < C_DIM) {
#pragma unroll
      for (int mt = 0; mt < 4; ++mt) {
#pragma unroll
        for (int r = 0; r < 4; ++r) {
          int row = mt * 16 + quad * 4 + r;
          float bias = 0.f;
#pragma unroll
          for (int e = 0; e < 8; ++e) bias += gt[e * 64 + row] * b2[e * C_DIM + c];
          out[(size_t)(r0 + row) * C_DIM + c] = acc2[mt][r] + bias;
        }
      }
    }
  }
}

extern "C" void kernel_launch(void* const* d_in, const int* in_sizes, int n_in,
                              void* d_out, int out_size, void* d_ws, size_t ws_size,
                              hipStream_t stream) {
  const float* x  = (const float*)d_in[0];
  const float* W1 = (const float*)d_in[1];
  const float* b1 = (const float*)d_in[2];
  const float* W2 = (const float*)d_in[3];
  const float* b2 = (const float*)d_in[4];
  const float* Wg = (const float*)d_in[5];
  const float* bg = (const float*)d_in[6];
  float* out = (float*)d_out;

  unsigned short* W1bf = (unsigned short*)d_ws;
  unsigned short* W2bf = (unsigned short*)((char*)d_ws + (size_t)129 * 16 * 512 * 2);

  conv_weights<<<644, 256, 0, stream>>>(W1, Wg, W2, W1bf, W2bf);  // 516 + 128 blocks
  moe_main<<<1024, 512, 0, stream>>>(x, b1, b2, bg, W1bf, W2bf, out);
}